// Round 10
// baseline (294.963 us; speedup 1.0000x reference)
//
#include <hip/hip_runtime.h>

#define N_NODES 100000
#define SCAN_NB 128
#define SCAN_TPB 256
#define GCOUNT 8      // node-range groups (GCOUNT * BINS == N_NODES)
#define BINS 12500    // bins per group -> 50 KB LDS histogram
#define NSLICE 32     // edge slices (per-slice u16 partial hists)

typedef _Float16 half_t;
typedef __attribute__((ext_vector_type(8))) _Float16 v8h;
typedef __attribute__((ext_vector_type(4))) _Float16 v4h;
typedef __attribute__((ext_vector_type(4))) float v4f;

// ---------------- hist_all: binned LDS histograms (ZERO device atomics) -------
// R18: device atomics are transaction-rate-pinned (~23G/s, 32B coherence-point
// write each, address-independent — R16/R17). Per-block LDS histograms over
// 12500-bin node ranges instead; loc[e] = ds-atomic return = rank within
// (slice,bin). src-hist blocks and weight-convert tail blocks share the grid.

__global__ __launch_bounds__(512) void hist_all(
    const int* __restrict__ src, const int* __restrict__ dst,
    int* __restrict__ loc, unsigned short* __restrict__ partialI,
    unsigned short* __restrict__ partialO, int E,
    const float* __restrict__ W1, const float* __restrict__ W2,
    const float* __restrict__ W3, half_t* __restrict__ Wt1,
    half_t* __restrict__ Wt2, half_t* __restrict__ Wt3) {
    __shared__ int hist[BINS];
    const int bid = blockIdx.x;
    const int tid = threadIdx.x;
    if (bid < 2 * GCOUNT * NSLICE) {
        const bool isDst = bid < GCOUNT * NSLICE;
        const int b2 = isDst ? bid : bid - GCOUNT * NSLICE;
        const int g = b2 >> 5, s = b2 & (NSLICE - 1);
        const int gbase = g * BINS;
        for (int b = tid; b < BINS; b += 512) hist[b] = 0;
        __syncthreads();
        const int chunk = (E + NSLICE - 1) / NSLICE;
        const int e0 = s * chunk;
        const int e1 = min(e0 + chunk, E);
        if (isDst) {
            for (int e = e0 + tid; e < e1; e += 512) {
                int d = dst[e];
                unsigned lb = (unsigned)(d - gbase);
                if (lb < (unsigned)BINS) loc[e] = atomicAdd(&hist[lb], 1);
            }
        } else {
            for (int e = e0 + tid; e < e1; e += 512) {
                int d = src[e];
                unsigned lb = (unsigned)(d - gbase);
                if (lb < (unsigned)BINS) atomicAdd(&hist[lb], 1);
            }
        }
        __syncthreads();
        unsigned short* p = (isDst ? partialI : partialO) + (size_t)b2 * BINS;
        for (int b = tid; b < BINS; b += 512) p[b] = (unsigned short)hist[b];
    } else {
        int u = (bid - 2 * GCOUNT * NSLICE) * 512 + tid;
        if (u < 32768) {                      // W1: K=128, N=256
            int n = u >> 7, k = u & 127;
            Wt1[u] = (half_t)W1[(size_t)k * 256 + n];
        } else if (u < 65536) {               // W2: K=256, N=128
            int w = u - 32768;
            int n = w >> 8, k = w & 255;
            Wt2[w] = (half_t)W2[(size_t)k * 128 + n];
        } else if (u < 70656) {               // W3: K=128, N=40
            int w = u - 65536;
            int n = w >> 7, k = w & 127;
            Wt3[w] = (half_t)W3[(size_t)k * 40 + n];
        }
    }
}

// ---------------- scan (3-phase hierarchical, over slice partials) -----------

__global__ __launch_bounds__(SCAN_TPB) void scan_reduce(
    const unsigned short* __restrict__ partialI, int* __restrict__ blockSum, int n) {
    __shared__ int s[SCAN_TPB];
    int chunk = (n + SCAN_NB - 1) / SCAN_NB;
    int beg = blockIdx.x * chunk;
    int end = min(beg + chunk, n);
    int sum = 0;
    for (int i = beg + threadIdx.x; i < end; i += SCAN_TPB) {
        int g = i / BINS, lb = i - g * BINS;
        const unsigned short* p = partialI + (size_t)g * NSLICE * BINS + lb;
#pragma unroll
        for (int sl = 0; sl < NSLICE; ++sl) sum += p[(size_t)sl * BINS];
    }
    s[threadIdx.x] = sum;
    __syncthreads();
    for (int off = SCAN_TPB / 2; off > 0; off >>= 1) {
        if (threadIdx.x < off) s[threadIdx.x] += s[threadIdx.x + off];
        __syncthreads();
    }
    if (threadIdx.x == 0) blockSum[blockIdx.x] = s[0];
}

__global__ __launch_bounds__(SCAN_NB) void scan_offsets(int* __restrict__ blockSum,
                                                        int* __restrict__ rowptr_total) {
    __shared__ int s[SCAN_NB];
    int tid = threadIdx.x;
    int v = blockSum[tid];
    s[tid] = v;
    __syncthreads();
    for (int off = 1; off < SCAN_NB; off <<= 1) {
        int t = (tid >= off) ? s[tid - off] : 0;
        __syncthreads();
        s[tid] += t;
        __syncthreads();
    }
    blockSum[tid] = s[tid] - v;
    if (tid == SCAN_NB - 1) rowptr_total[0] = s[tid];
}

// Phase 3: rowptr via in-chunk scan + block offset; partialI converted in-place
// to an exclusive slice-prefix per bin; degree sums -> inv-sqrt norms.
__global__ __launch_bounds__(SCAN_TPB) void scan_final(
    unsigned short* __restrict__ partialI, const unsigned short* __restrict__ partialO,
    const int* __restrict__ blockSum, int* __restrict__ rowptr,
    float* __restrict__ invIn, float* __restrict__ invOut, int n) {
    __shared__ int s[SCAN_TPB];
    int chunk = (n + SCAN_NB - 1) / SCAN_NB;
    int beg = blockIdx.x * chunk;
    int end = min(beg + chunk, n);
    int carry = blockSum[blockIdx.x];
    for (int base = beg; base < end; base += SCAN_TPB) {
        int i = base + threadIdx.x;
        int v = 0, o = 0;
        if (i < end) {
            int g = i / BINS, lb = i - g * BINS;
            unsigned short* p = partialI + (size_t)g * NSLICE * BINS + lb;
            int run = 0;
#pragma unroll
            for (int sl = 0; sl < NSLICE; ++sl) {   // exclusive prefix over slices
                int c = p[(size_t)sl * BINS];
                p[(size_t)sl * BINS] = (unsigned short)run;
                run += c;
            }
            v = run;
            const unsigned short* q = partialO + (size_t)g * NSLICE * BINS + lb;
#pragma unroll
            for (int sl = 0; sl < NSLICE; ++sl) o += q[(size_t)sl * BINS];
        }
        s[threadIdx.x] = v;
        __syncthreads();
        for (int off = 1; off < SCAN_TPB; off <<= 1) {
            int t = (threadIdx.x >= off) ? s[threadIdx.x - off] : 0;
            __syncthreads();
            s[threadIdx.x] += t;
            __syncthreads();
        }
        int excl = s[threadIdx.x] - v;
        if (i < end) {
            rowptr[i] = carry + excl;
            invOut[i] = rsqrtf((float)max(o, 1));
            invIn[i] = rsqrtf((float)max(v, 1));
        }
        int roundSum = s[SCAN_TPB - 1];
        __syncthreads();
        carry += roundSum;
    }
}

// ---------------- prep2: atomic-free CSR fill + x convert ----------------
// pos = rowptr[dst] + slice-prefix (u16, LLC-resident) + loc (coalesced).

__global__ void prep2(const int* __restrict__ src, const int* __restrict__ dst,
                      const int* __restrict__ loc,
                      const unsigned short* __restrict__ partialI,
                      const int* __restrict__ rowptr,
                      int* __restrict__ eidx, int E,
                      const float* __restrict__ x, const float* __restrict__ invOut,
                      half_t* __restrict__ xh) {
    int t = blockIdx.x * blockDim.x + threadIdx.x;
    if (t < E) {
        int d = dst[t];
        int chunk = (E + NSLICE - 1) / NSLICE;
        int s = t / chunk;
        int g = d / BINS, lb = d - g * BINS;
        int pre = partialI[(size_t)(g * NSLICE + s) * BINS + lb];
        eidx[rowptr[d] + pre + loc[t]] = src[t];
    } else {
        int u = t - E;
        if (u < N_NODES * 32) {
            int n = u >> 5;
            float4 v = ((const float4*)x)[u];
            float s = invOut[n];
            v4h h;
            h[0] = (half_t)(v.x * s);
            h[1] = (half_t)(v.y * s);
            h[2] = (half_t)(v.z * s);
            h[3] = (half_t)(v.w * s);
            *(v4h*)(xh + (size_t)u * 4) = h;
        }
    }
}

// ---------------- CSR row segment-sum into fp32 acc[8] ----------------
// R11: idx prefetch one batch ahead (counted vmcnt, idx latency under accum).
// R13: dual-row interleave regressed — single row per thread is the keeper.
// R19: masked final batch (clamped idx + cndmask-zeroed overhang) — the 1-3
// edge scalar tail was a serialized latency chain per row.

template <int F>
__device__ __forceinline__ void gather_row(const half_t* __restrict__ x,
                                           const int* __restrict__ eidx,
                                           int beg, int end, int c, float* acc) {
    const half_t* __restrict__ xc = x + (size_t)c * 8;
    int n = end - beg;
    if (n <= 0) return;
    int nbat = (n + 3) >> 2;
    int i0 = eidx[beg];
    int i1 = eidx[beg + min(1, n - 1)];
    int i2 = eidx[beg + min(2, n - 1)];
    int i3 = eidx[beg + min(3, n - 1)];
    for (int b = 0; b < nbat; ++b) {
        int j = b * 4;
        v8h v0 = *(const v8h*)(xc + (size_t)i0 * F);
        v8h v1 = *(const v8h*)(xc + (size_t)i1 * F);
        v8h v2 = *(const v8h*)(xc + (size_t)i2 * F);
        v8h v3 = *(const v8h*)(xc + (size_t)i3 * F);
        if (b + 1 < nbat) {                    // prefetch next batch's indices
            int jn = j + 4;                    // (independent of v0..v3 -> stays
            i0 = eidx[beg + jn];               //  in flight across the data wait)
            i1 = eidx[beg + min(jn + 1, n - 1)];
            i2 = eidx[beg + min(jn + 2, n - 1)];
            i3 = eidx[beg + min(jn + 3, n - 1)];
        }
        // zero overhang lanes (only meaningful in the last batch)
        v8h z = (v8h)(half_t)0;
        v1 = (j + 1 < n) ? v1 : z;
        v2 = (j + 2 < n) ? v2 : z;
        v3 = (j + 3 < n) ? v3 : z;
#pragma unroll
        for (int q = 0; q < 8; ++q)
            acc[q] += ((float)v0[q] + (float)v1[q]) + ((float)v2[q] + (float)v3[q]);
    }
}

// ---------------- standalone gather kernels (no LDS, no barriers) --------
// R14: barrier-free at 32 waves/CU. R20: SPLIT-ROW — 32 lanes/row, two 16-lane
// half-groups gather each half of the edge list, partials combined with 8
// shfl_xor(16) (wave-internal, no LDS). Per-thread serial chain halves; loads
// issued and bytes moved unchanged. This is also the latency-vs-LLC-BW
// discriminator: null result => gathers are BW/issue-bound (near floor).

__global__ __launch_bounds__(256, 8) void gather1(
    const half_t* __restrict__ xh, const int* __restrict__ rowptr,
    const int* __restrict__ eidx, half_t* __restrict__ A1) {
    int t = blockIdx.x * 256 + threadIdx.x;
    int n = t >> 5;
    if (n >= N_NODES) return;
    int l32 = t & 31, half = l32 >> 4, c = l32 & 15;
    int beg = rowptr[n], end = rowptr[n + 1];
    int h = (end - beg + 1) >> 1;       // half 0: [beg, beg+h), half 1: [beg+h, end)
    int b0 = half ? beg + h : beg;
    int e0 = half ? end : beg + h;
    float acc[8] = {};
    gather_row<128>(xh, eidx, b0, e0, c, acc);
#pragma unroll
    for (int q = 0; q < 8; ++q) acc[q] += __shfl_xor(acc[q], 16);
    if (!half) {
        v8h o;
#pragma unroll
        for (int q = 0; q < 8; ++q) o[q] = (half_t)acc[q];
        *(v8h*)(A1 + (size_t)n * 128 + c * 8) = o;
    }
}

// gather2: segsum(t2) with fused layer-2 epilogue:
//   A2 = relu((g*invIn + b2)*invOut) in fp16 (pre-scaled for layer-3 agg).
__global__ __launch_bounds__(256, 8) void gather2(
    const half_t* __restrict__ t2, const int* __restrict__ rowptr,
    const int* __restrict__ eidx, const float* __restrict__ invIn,
    const float* __restrict__ invOut, const float* __restrict__ b2,
    half_t* __restrict__ A2) {
    int t = blockIdx.x * 256 + threadIdx.x;
    int n = t >> 5;
    if (n >= N_NODES) return;
    int l32 = t & 31, half = l32 >> 4, c = l32 & 15;
    int beg = rowptr[n], end = rowptr[n + 1];
    int h = (end - beg + 1) >> 1;
    int b0 = half ? beg + h : beg;
    int e0 = half ? end : beg + h;
    float acc[8] = {};
    gather_row<128>(t2, eidx, b0, e0, c, acc);
#pragma unroll
    for (int q = 0; q < 8; ++q) acc[q] += __shfl_xor(acc[q], 16);
    if (!half) {
        float ii = invIn[n], io = invOut[n];
        float4 blo = ((const float4*)b2)[c * 2];
        float4 bhi = ((const float4*)b2)[c * 2 + 1];
        float bb[8] = {blo.x, blo.y, blo.z, blo.w, bhi.x, bhi.y, bhi.z, bhi.w};
        v8h o;
#pragma unroll
        for (int q = 0; q < 8; ++q)
            o[q] = (half_t)fmaxf((acc[q] * ii + bb[q]) * io, 0.f);
        *(v8h*)(A2 + (size_t)n * 128 + c * 8) = o;
    }
}

// ---------------- dense MLP kernels (uniform, MFMA-bound) ----------------
// mlp12: t2 = (relu((A1@W1)*invIn + b1)*invOut) @ W2.

__global__ __launch_bounds__(512) void mlp12(
    const half_t* __restrict__ A1, const half_t* __restrict__ Wt1,
    const half_t* __restrict__ Wt2,
    const float* __restrict__ invIn, const float* __restrict__ invOut,
    const float* __restrict__ b1, half_t* __restrict__ t2) {
    constexpr int K1 = 128, K2 = 256, N2 = 128;
    constexpr int LDA = K1 + 8;
    constexpr int LDH = K2 + 8;
    __shared__ half_t As[64][LDA];
    __shared__ half_t h1S[64][LDH];
    __shared__ float iiS[64], ioS[64];
    const int tid = threadIdx.x;
    const int wave = tid >> 6, lane = tid & 63;
    const int quad = lane >> 4, l16 = lane & 15;
    const int m0 = blockIdx.x * 64;
    const int n0 = wave * 32;   // GEMM1 column span per wave (8 waves x 32 = 256)

    // B1 fragments into registers (overlap with A-load)
    v8h b[2][4];
    float bv[2];
#pragma unroll
    for (int j = 0; j < 2; ++j) {
        int gn = n0 + j * 16 + l16;
        bv[j] = b1[gn];
#pragma unroll
        for (int kc = 0; kc < 4; ++kc)
            b[j][kc] = *(const v8h*)(Wt1 + (size_t)gn * K1 + kc * 32 + quad * 8);
    }
    if (tid < 64) {
        int gm = m0 + tid;
        bool ok = gm < N_NODES;
        iiS[tid] = ok ? invIn[gm] : 0.f;
        ioS[tid] = ok ? invOut[gm] : 0.f;
    }

    // A-tile load: 64 rows x 16 chunks = 1024 dwordx4, 2 per thread (coalesced)
#pragma unroll
    for (int p = 0; p < 2; ++p) {
        int task = tid + p * 512;
        int r = task >> 4, c = task & 15;
        int gm = m0 + r;
        v8h v = (gm < N_NODES) ? *(const v8h*)(A1 + (size_t)gm * K1 + c * 8)
                               : (v8h)(half_t)0;
        *(v8h*)&As[r][c * 8] = v;
    }
    __syncthreads();

    // GEMM1 -> h1S (LDS): 4 m-tiles x 2 n-tiles per wave
    for (int mt = 0; mt < 4; ++mt) {
        v8h a[4];
#pragma unroll
        for (int kc = 0; kc < 4; ++kc)
            a[kc] = *(const v8h*)&As[mt * 16 + l16][kc * 32 + quad * 8];
        v4f acc[2] = {};
#pragma unroll
        for (int kc = 0; kc < 4; ++kc)
#pragma unroll
            for (int j = 0; j < 2; ++j)
                acc[j] = __builtin_amdgcn_mfma_f32_16x16x32_f16(a[kc], b[j][kc], acc[j], 0, 0, 0);
#pragma unroll
        for (int j = 0; j < 2; ++j) {
            int cn = n0 + j * 16 + l16;
#pragma unroll
            for (int r = 0; r < 4; ++r) {
                int lr = mt * 16 + quad * 4 + r;
                float z = (acc[j][r] * iiS[lr] + bv[j]) * ioS[lr];
                h1S[lr][cn] = (half_t)fmaxf(z, 0.f);
            }
        }
    }

    // B2 fragments: 1 n-tile per wave (8 x 16 = 128 cols)
    v8h b2[8];
    const int n02 = wave * 16;
    {
        int gn = n02 + l16;
#pragma unroll
        for (int kc = 0; kc < 8; ++kc)
            b2[kc] = *(const v8h*)(Wt2 + (size_t)gn * K2 + kc * 32 + quad * 8);
    }
    __syncthreads();

    // GEMM2: t2 = h1S @ W2
    for (int mt = 0; mt < 4; ++mt) {
        v8h a2[8];
#pragma unroll
        for (int kc = 0; kc < 8; ++kc)
            a2[kc] = *(const v8h*)&h1S[mt * 16 + l16][kc * 32 + quad * 8];
        v4f acc2 = {};
#pragma unroll
        for (int kc = 0; kc < 8; ++kc)
            acc2 = __builtin_amdgcn_mfma_f32_16x16x32_f16(a2[kc], b2[kc], acc2, 0, 0, 0);
        int gn = n02 + l16;
#pragma unroll
        for (int r = 0; r < 4; ++r) {
            int gm = m0 + mt * 16 + quad * 4 + r;
            if (gm < N_NODES) t2[(size_t)gm * N2 + gn] = (half_t)acc2[r];
        }
    }
}

// mlp3: t3 = A2 @ W3 (A2 already relu'd + pre-scaled by gather2's epilogue).

__global__ __launch_bounds__(256) void mlp3(
    const half_t* __restrict__ A2, const half_t* __restrict__ Wt3,
    half_t* __restrict__ t3) {
    constexpr int K = 128, N = 40, LDA = K + 8;
    __shared__ half_t As[64][LDA];
    const int tid = threadIdx.x;
    const int wave = tid >> 6, lane = tid & 63;
    const int quad = lane >> 4, l16 = lane & 15;
    const int m0 = blockIdx.x * 64;

    v8h b[3][4];
#pragma unroll
    for (int j = 0; j < 3; ++j) {
        int gn = j * 16 + l16;
#pragma unroll
        for (int kc = 0; kc < 4; ++kc)
            b[j][kc] = (gn < N) ? *(const v8h*)(Wt3 + (size_t)gn * K + kc * 32 + quad * 8)
                                : (v8h)(half_t)0;
    }

#pragma unroll
    for (int p = 0; p < 4; ++p) {
        int task = tid + p * 256;
        int r = task >> 4, c = task & 15;
        int gm = m0 + r;
        v8h v = (gm < N_NODES) ? *(const v8h*)(A2 + (size_t)gm * K + c * 8)
                               : (v8h)(half_t)0;
        *(v8h*)&As[r][c * 8] = v;
    }
    __syncthreads();

    {
        int mt = wave;
        v8h a[4];
#pragma unroll
        for (int kc = 0; kc < 4; ++kc)
            a[kc] = *(const v8h*)&As[mt * 16 + l16][kc * 32 + quad * 8];
        v4f acc[3] = {};
#pragma unroll
        for (int kc = 0; kc < 4; ++kc)
#pragma unroll
            for (int j = 0; j < 3; ++j)
                acc[j] = __builtin_amdgcn_mfma_f32_16x16x32_f16(a[kc], b[j][kc], acc[j], 0, 0, 0);
#pragma unroll
        for (int j = 0; j < 3; ++j) {
            int gn = j * 16 + l16;
            if (gn >= N) continue;
#pragma unroll
            for (int r = 0; r < 4; ++r) {
                int gm = m0 + mt * 16 + quad * 4 + r;
                if (gm < N_NODES) t3[(size_t)gm * N + gn] = (half_t)acc[j][r];
            }
        }
    }
}

// ---------------- final gather (fp16 rows, fp32 out) ----------------

__global__ __launch_bounds__(256, 8) void gather_final(
    const half_t* __restrict__ x,
    const int* __restrict__ rowptr, const int* __restrict__ eidx,
    float* __restrict__ out, const float* __restrict__ invIn,
    const float* __restrict__ bias) {
    constexpr int F = 40, V = 5;
    int t = blockIdx.x * blockDim.x + threadIdx.x;
    int n = t / V;
    int v = t - n * V;
    if (n >= N_NODES) return;
    float acc[8] = {};
    gather_row<F>(x, eidx, rowptr[n], rowptr[n + 1], v, acc);
    float ii = invIn[n];
    float* o = out + (size_t)n * F + v * 8;
#pragma unroll
    for (int q = 0; q < 8; ++q) o[q] = acc[q] * ii + bias[v * 8 + q];
}

// ---------------- launch ----------------

extern "C" void kernel_launch(void* const* d_in, const int* in_sizes, int n_in,
                              void* d_out, int out_size, void* d_ws, size_t ws_size,
                              hipStream_t stream) {
    const float* x  = (const float*)d_in[0];
    const int* src  = (const int*)d_in[1];
    const int* dst  = (const int*)d_in[2];
    const float* W1 = (const float*)d_in[3];
    const float* b1 = (const float*)d_in[4];
    const float* W2 = (const float*)d_in[5];
    const float* b2 = (const float*)d_in[6];
    const float* W3 = (const float*)d_in[7];
    const float* b3 = (const float*)d_in[8];
    float* out = (float*)d_out;
    const int E = in_sizes[1];

    char* ws = (char*)d_ws;
    float* inv_out = (float*)ws;                  // 400 KB (written by scan_final)
    float* inv_in  = (float*)(ws + 400000);       // 400 KB
    int* rowptr    = (int*)(ws + 800000);         // 100001
    int* eidx      = (int*)(ws + 1600256);        // 800000 (3.2 MB)
    int* blockSum  = (int*)(ws + 4800256);        // 128
    half_t* Wt1    = (half_t*)(ws + 4800768);     // 256x128 fp16 (64 KB)
    half_t* Wt2    = (half_t*)(ws + 4866304);     // 128x256 fp16 (64 KB)
    half_t* Wt3    = (half_t*)(ws + 4931840);     // 40x128 fp16 (10 KB)
    half_t* bufA   = (half_t*)(ws + 5000192);     // 25.6 MB: xh -> t2 -> t3
    half_t* bufB   = (half_t*)(ws + 30600192);    // 25.6 MB: prep overlays -> A1 -> A2
    // bufB overlays (all dead before gather1 writes A1):
    int* loc = (int*)bufB;                                        // E ints (3.2 MB)
    unsigned short* partialI = (unsigned short*)((char*)bufB + 3200000);  // 32xN u16 (6.4 MB)
    unsigned short* partialO = partialI + (size_t)GCOUNT * NSLICE * BINS; // 6.4 MB

    // ---- CSR + norms + weight conversion (no memset needed: everything
    //      below is fully overwritten) ----
    const int NBH = 2 * GCOUNT * NSLICE + (70656 + 511) / 512;  // 512 hist + 138 tail
    hist_all<<<NBH, 512, 0, stream>>>(src, dst, loc, partialI, partialO, E,
                                      W1, W2, W3, Wt1, Wt2, Wt3);
    scan_reduce<<<SCAN_NB, SCAN_TPB, 0, stream>>>(partialI, blockSum, N_NODES);
    scan_offsets<<<1, SCAN_NB, 0, stream>>>(blockSum, rowptr + N_NODES);
    scan_final<<<SCAN_NB, SCAN_TPB, 0, stream>>>(partialI, partialO, blockSum, rowptr,
                                                 inv_in, inv_out, N_NODES);
    prep2<<<(E + N_NODES * 32 + 255) / 256, 256, 0, stream>>>(src, dst, loc, partialI,
                                                              rowptr, eidx, E,
                                                              x, inv_out, bufA);

    const int NBG = (N_NODES * 32 + 255) / 256;  // 12500 (split-row gather: 32 thr/row)
    const int NB  = (N_NODES + 63) / 64;         // 1563 (MLP: 64-row tiles)

    // Layer 1 aggregation: A1 = segsum(xh)          (reads bufA, writes bufB; overlays dead)
    gather1<<<NBG, 256, 0, stream>>>(bufA, rowptr, eidx, bufB);
    // Layers 1+2 transform: t2 = MLP(A1)            (reads bufB, writes bufA; xh dead)
    mlp12<<<NB, 512, 0, stream>>>(bufB, Wt1, Wt2, inv_in, inv_out, b1, bufA);
    // Layer 2 aggregation + epilogue: A2            (reads bufA, writes bufB; A1 dead)
    gather2<<<NBG, 256, 0, stream>>>(bufA, rowptr, eidx, inv_in, inv_out, b2, bufB);
    // Layer 3 transform: t3 = A2 @ W3               (reads bufB, writes bufA; t2 dead)
    mlp3<<<NB, 256, 0, stream>>>(bufB, Wt3, bufA);
    // Final aggregation: out = segsum(t3)*inv_in+b3 (reads bufA)
    gather_final<<<(N_NODES * 5 + 255) / 256, 256, 0, stream>>>(
        bufA, rowptr, eidx, out, inv_in, b3);
}

// Round 11
// 282.930 us; speedup vs baseline: 1.0425x; 1.0425x over previous
//
#include <hip/hip_runtime.h>

#define N_NODES 100000
#define SCAN_NB 128
#define SCAN_TPB 256
#define GCOUNT 8      // node-range groups (GCOUNT * BINS == N_NODES)
#define BINS 12500    // bins per group -> 50 KB LDS histogram
#define NSLICE 32     // edge slices (per-slice u16 partial hists)

typedef _Float16 half_t;
typedef __attribute__((ext_vector_type(8))) _Float16 v8h;
typedef __attribute__((ext_vector_type(4))) _Float16 v4h;
typedef __attribute__((ext_vector_type(4))) float v4f;

// ---------------- hist_all: binned LDS histograms (ZERO device atomics) -------
// R18: device atomics are transaction-rate-pinned (~23G/s, 32B coherence-point
// write each, address-independent — R16/R17). Per-block LDS histograms over
// 12500-bin node ranges instead; loc[e] = ds-atomic return = rank within
// (slice,bin). src-hist blocks and weight-convert tail blocks share the grid.

__global__ __launch_bounds__(512) void hist_all(
    const int* __restrict__ src, const int* __restrict__ dst,
    int* __restrict__ loc, unsigned short* __restrict__ partialI,
    unsigned short* __restrict__ partialO, int E,
    const float* __restrict__ W1, const float* __restrict__ W2,
    const float* __restrict__ W3, half_t* __restrict__ Wt1,
    half_t* __restrict__ Wt2, half_t* __restrict__ Wt3) {
    __shared__ int hist[BINS];
    const int bid = blockIdx.x;
    const int tid = threadIdx.x;
    if (bid < 2 * GCOUNT * NSLICE) {
        const bool isDst = bid < GCOUNT * NSLICE;
        const int b2 = isDst ? bid : bid - GCOUNT * NSLICE;
        const int g = b2 >> 5, s = b2 & (NSLICE - 1);
        const int gbase = g * BINS;
        for (int b = tid; b < BINS; b += 512) hist[b] = 0;
        __syncthreads();
        const int chunk = (E + NSLICE - 1) / NSLICE;
        const int e0 = s * chunk;
        const int e1 = min(e0 + chunk, E);
        if (isDst) {
            for (int e = e0 + tid; e < e1; e += 512) {
                int d = dst[e];
                unsigned lb = (unsigned)(d - gbase);
                if (lb < (unsigned)BINS) loc[e] = atomicAdd(&hist[lb], 1);
            }
        } else {
            for (int e = e0 + tid; e < e1; e += 512) {
                int d = src[e];
                unsigned lb = (unsigned)(d - gbase);
                if (lb < (unsigned)BINS) atomicAdd(&hist[lb], 1);
            }
        }
        __syncthreads();
        unsigned short* p = (isDst ? partialI : partialO) + (size_t)b2 * BINS;
        for (int b = tid; b < BINS; b += 512) p[b] = (unsigned short)hist[b];
    } else {
        int u = (bid - 2 * GCOUNT * NSLICE) * 512 + tid;
        if (u < 32768) {                      // W1: K=128, N=256
            int n = u >> 7, k = u & 127;
            Wt1[u] = (half_t)W1[(size_t)k * 256 + n];
        } else if (u < 65536) {               // W2: K=256, N=128
            int w = u - 32768;
            int n = w >> 8, k = w & 255;
            Wt2[w] = (half_t)W2[(size_t)k * 128 + n];
        } else if (u < 70656) {               // W3: K=128, N=40
            int w = u - 65536;
            int n = w >> 7, k = w & 127;
            Wt3[w] = (half_t)W3[(size_t)k * 40 + n];
        }
    }
}

// ---------------- scan (3-phase hierarchical, over slice partials) -----------

__global__ __launch_bounds__(SCAN_TPB) void scan_reduce(
    const unsigned short* __restrict__ partialI, int* __restrict__ blockSum, int n) {
    __shared__ int s[SCAN_TPB];
    int chunk = (n + SCAN_NB - 1) / SCAN_NB;
    int beg = blockIdx.x * chunk;
    int end = min(beg + chunk, n);
    int sum = 0;
    for (int i = beg + threadIdx.x; i < end; i += SCAN_TPB) {
        int g = i / BINS, lb = i - g * BINS;
        const unsigned short* p = partialI + (size_t)g * NSLICE * BINS + lb;
#pragma unroll
        for (int sl = 0; sl < NSLICE; ++sl) sum += p[(size_t)sl * BINS];
    }
    s[threadIdx.x] = sum;
    __syncthreads();
    for (int off = SCAN_TPB / 2; off > 0; off >>= 1) {
        if (threadIdx.x < off) s[threadIdx.x] += s[threadIdx.x + off];
        __syncthreads();
    }
    if (threadIdx.x == 0) blockSum[blockIdx.x] = s[0];
}

__global__ __launch_bounds__(SCAN_NB) void scan_offsets(int* __restrict__ blockSum,
                                                        int* __restrict__ rowptr_total) {
    __shared__ int s[SCAN_NB];
    int tid = threadIdx.x;
    int v = blockSum[tid];
    s[tid] = v;
    __syncthreads();
    for (int off = 1; off < SCAN_NB; off <<= 1) {
        int t = (tid >= off) ? s[tid - off] : 0;
        __syncthreads();
        s[tid] += t;
        __syncthreads();
    }
    blockSum[tid] = s[tid] - v;
    if (tid == SCAN_NB - 1) rowptr_total[0] = s[tid];
}

// Phase 3: rowptr via in-chunk scan + block offset; partialI converted in-place
// to an exclusive slice-prefix per bin; degree sums -> inv-sqrt norms.
__global__ __launch_bounds__(SCAN_TPB) void scan_final(
    unsigned short* __restrict__ partialI, const unsigned short* __restrict__ partialO,
    const int* __restrict__ blockSum, int* __restrict__ rowptr,
    float* __restrict__ invIn, float* __restrict__ invOut, int n) {
    __shared__ int s[SCAN_TPB];
    int chunk = (n + SCAN_NB - 1) / SCAN_NB;
    int beg = blockIdx.x * chunk;
    int end = min(beg + chunk, n);
    int carry = blockSum[blockIdx.x];
    for (int base = beg; base < end; base += SCAN_TPB) {
        int i = base + threadIdx.x;
        int v = 0, o = 0;
        if (i < end) {
            int g = i / BINS, lb = i - g * BINS;
            unsigned short* p = partialI + (size_t)g * NSLICE * BINS + lb;
            int run = 0;
#pragma unroll
            for (int sl = 0; sl < NSLICE; ++sl) {   // exclusive prefix over slices
                int c = p[(size_t)sl * BINS];
                p[(size_t)sl * BINS] = (unsigned short)run;
                run += c;
            }
            v = run;
            const unsigned short* q = partialO + (size_t)g * NSLICE * BINS + lb;
#pragma unroll
            for (int sl = 0; sl < NSLICE; ++sl) o += q[(size_t)sl * BINS];
        }
        s[threadIdx.x] = v;
        __syncthreads();
        for (int off = 1; off < SCAN_TPB; off <<= 1) {
            int t = (threadIdx.x >= off) ? s[threadIdx.x - off] : 0;
            __syncthreads();
            s[threadIdx.x] += t;
            __syncthreads();
        }
        int excl = s[threadIdx.x] - v;
        if (i < end) {
            rowptr[i] = carry + excl;
            invOut[i] = rsqrtf((float)max(o, 1));
            invIn[i] = rsqrtf((float)max(v, 1));
        }
        int roundSum = s[SCAN_TPB - 1];
        __syncthreads();
        carry += roundSum;
    }
}

// ---------------- prep2: atomic-free CSR fill + x convert ----------------
// pos = rowptr[dst] + slice-prefix (u16, LLC-resident) + loc (coalesced).

__global__ void prep2(const int* __restrict__ src, const int* __restrict__ dst,
                      const int* __restrict__ loc,
                      const unsigned short* __restrict__ partialI,
                      const int* __restrict__ rowptr,
                      int* __restrict__ eidx, int E,
                      const float* __restrict__ x, const float* __restrict__ invOut,
                      half_t* __restrict__ xh) {
    int t = blockIdx.x * blockDim.x + threadIdx.x;
    if (t < E) {
        int d = dst[t];
        int chunk = (E + NSLICE - 1) / NSLICE;
        int s = t / chunk;
        int g = d / BINS, lb = d - g * BINS;
        int pre = partialI[(size_t)(g * NSLICE + s) * BINS + lb];
        eidx[rowptr[d] + pre + loc[t]] = src[t];
    } else {
        int u = t - E;
        if (u < N_NODES * 32) {
            int n = u >> 5;
            float4 v = ((const float4*)x)[u];
            float s = invOut[n];
            v4h h;
            h[0] = (half_t)(v.x * s);
            h[1] = (half_t)(v.y * s);
            h[2] = (half_t)(v.z * s);
            h[3] = (half_t)(v.w * s);
            *(v4h*)(xh + (size_t)u * 4) = h;
        }
    }
}

// ---------------- CSR row segment-sum into fp32 acc[8] ----------------
// R11: idx prefetch one batch ahead. R13: dual-row interleave regressed.
// R19: masked final batch (clamped idx + cndmask-zeroed overhang).
// R20: split-row (2x16-lane halves + shfl) was NULL -> gathers are VMEM-queue/
// LLC-BW-bound, not latency-chain-bound. Reverted to 16 lanes/row.

template <int F>
__device__ __forceinline__ void gather_row(const half_t* __restrict__ x,
                                           const int* __restrict__ eidx,
                                           int beg, int end, int c, float* acc) {
    const half_t* __restrict__ xc = x + (size_t)c * 8;
    int n = end - beg;
    if (n <= 0) return;
    int nbat = (n + 3) >> 2;
    int i0 = eidx[beg];
    int i1 = eidx[beg + min(1, n - 1)];
    int i2 = eidx[beg + min(2, n - 1)];
    int i3 = eidx[beg + min(3, n - 1)];
    for (int b = 0; b < nbat; ++b) {
        int j = b * 4;
        v8h v0 = *(const v8h*)(xc + (size_t)i0 * F);
        v8h v1 = *(const v8h*)(xc + (size_t)i1 * F);
        v8h v2 = *(const v8h*)(xc + (size_t)i2 * F);
        v8h v3 = *(const v8h*)(xc + (size_t)i3 * F);
        if (b + 1 < nbat) {                    // prefetch next batch's indices
            int jn = j + 4;
            i0 = eidx[beg + jn];
            i1 = eidx[beg + min(jn + 1, n - 1)];
            i2 = eidx[beg + min(jn + 2, n - 1)];
            i3 = eidx[beg + min(jn + 3, n - 1)];
        }
        v8h z = (v8h)(half_t)0;
        v1 = (j + 1 < n) ? v1 : z;
        v2 = (j + 2 < n) ? v2 : z;
        v3 = (j + 3 < n) ? v3 : z;
#pragma unroll
        for (int q = 0; q < 8; ++q)
            acc[q] += ((float)v0[q] + (float)v1[q]) + ((float)v2[q] + (float)v3[q]);
    }
}

// ---------------- gather1: standalone (no LDS, no barriers) --------

__global__ __launch_bounds__(256, 8) void gather1(
    const half_t* __restrict__ xh, const int* __restrict__ rowptr,
    const int* __restrict__ eidx, half_t* __restrict__ A1) {
    int t = blockIdx.x * 256 + threadIdx.x;
    int n = t >> 4, c = t & 15;
    if (n >= N_NODES) return;
    float acc[8] = {};
    gather_row<128>(xh, eidx, rowptr[n], rowptr[n + 1], c, acc);
    v8h o;
#pragma unroll
    for (int q = 0; q < 8; ++q) o[q] = (half_t)acc[q];
    *(v8h*)(A1 + (size_t)n * 128 + c * 8) = o;
}

// ---------------- R21: gather2 + mlp3 FUSED ----------------
// gather2->mlp3 has NO aggregation boundary (per-node pipeline): fuse them.
// 32 rows x 16 lanes = 512 threads, exact R19 gather task structure; the
// epilogued A2 tile goes to a tiny 8.7KB LDS buffer; waves 0-5 run the
// 16x128 @ 128x40 MFMA and write t3. Eliminates the 51.2MB A2 round-trip
// and one launch; W3-frag reload is ~75MB L2-resident (~3us).

__global__ __launch_bounds__(512) void gather2t3(
    const half_t* __restrict__ t2, const int* __restrict__ rowptr,
    const int* __restrict__ eidx, const float* __restrict__ invIn,
    const float* __restrict__ invOut, const float* __restrict__ b2,
    const half_t* __restrict__ Wt3, half_t* __restrict__ t3) {
    constexpr int K = 128, N = 40, LDA = K + 8;
    __shared__ half_t As[32][LDA];
    const int tid = threadIdx.x;
    const int wave = tid >> 6, lane = tid & 63;
    const int quad = lane >> 4, l16 = lane & 15;
    const int m0 = blockIdx.x * 32;
    const int mt = wave & 1, jn = wave >> 1;   // (m-tile, n-tile) for epilogue

    // B3 fragment for this wave's n-tile (waves 0..5 active in epilogue)
    v8h b[4];
    if (jn < 3) {
        int gn = jn * 16 + l16;
#pragma unroll
        for (int kc = 0; kc < 4; ++kc)
            b[kc] = (gn < N) ? *(const v8h*)(Wt3 + (size_t)gn * K + kc * 32 + quad * 8)
                             : (v8h)(half_t)0;
    }

    // gather phase: 32 rows x 16 chunks = 512 tasks, exactly 1 per thread
    {
        int r = tid >> 4, c = tid & 15;
        int n = m0 + r;
        float acc[8] = {};
        float ii = 0.f, io = 0.f;
        if (n < N_NODES) {
            ii = invIn[n];
            io = invOut[n];
            gather_row<128>(t2, eidx, rowptr[n], rowptr[n + 1], c, acc);
        }
        float4 blo = ((const float4*)b2)[c * 2];
        float4 bhi = ((const float4*)b2)[c * 2 + 1];
        float bb[8] = {blo.x, blo.y, blo.z, blo.w, bhi.x, bhi.y, bhi.z, bhi.w};
        v8h o;
#pragma unroll
        for (int q = 0; q < 8; ++q)
            o[q] = (half_t)fmaxf((acc[q] * ii + bb[q]) * io, 0.f);
        *(v8h*)&As[r][c * 8] = o;
    }
    __syncthreads();

    // MFMA epilogue: t3[m-tile] = A2tile @ W3
    if (jn < 3) {
        v8h a[4];
#pragma unroll
        for (int kc = 0; kc < 4; ++kc)
            a[kc] = *(const v8h*)&As[mt * 16 + l16][kc * 32 + quad * 8];
        v4f acc = {};
#pragma unroll
        for (int kc = 0; kc < 4; ++kc)
            acc = __builtin_amdgcn_mfma_f32_16x16x32_f16(a[kc], b[kc], acc, 0, 0, 0);
        int gn = jn * 16 + l16;
        if (gn < N) {
#pragma unroll
            for (int r = 0; r < 4; ++r) {
                int gm = m0 + mt * 16 + quad * 4 + r;
                if (gm < N_NODES) t3[(size_t)gm * N + gn] = (half_t)acc[r];
            }
        }
    }
}

// ---------------- dense MLP kernel (uniform, MFMA-bound) ----------------
// mlp12: t2 = (relu((A1@W1)*invIn + b1)*invOut) @ W2. (NOT fused with gather1:
// per-block W1+W2 fragment reload would be ~600MB of L2 traffic at 16-row
// blocks — the R2 lesson.)

__global__ __launch_bounds__(512) void mlp12(
    const half_t* __restrict__ A1, const half_t* __restrict__ Wt1,
    const half_t* __restrict__ Wt2,
    const float* __restrict__ invIn, const float* __restrict__ invOut,
    const float* __restrict__ b1, half_t* __restrict__ t2) {
    constexpr int K1 = 128, K2 = 256, N2 = 128;
    constexpr int LDA = K1 + 8;
    constexpr int LDH = K2 + 8;
    __shared__ half_t As[64][LDA];
    __shared__ half_t h1S[64][LDH];
    __shared__ float iiS[64], ioS[64];
    const int tid = threadIdx.x;
    const int wave = tid >> 6, lane = tid & 63;
    const int quad = lane >> 4, l16 = lane & 15;
    const int m0 = blockIdx.x * 64;
    const int n0 = wave * 32;   // GEMM1 column span per wave (8 waves x 32 = 256)

    // B1 fragments into registers (overlap with A-load)
    v8h b[2][4];
    float bv[2];
#pragma unroll
    for (int j = 0; j < 2; ++j) {
        int gn = n0 + j * 16 + l16;
        bv[j] = b1[gn];
#pragma unroll
        for (int kc = 0; kc < 4; ++kc)
            b[j][kc] = *(const v8h*)(Wt1 + (size_t)gn * K1 + kc * 32 + quad * 8);
    }
    if (tid < 64) {
        int gm = m0 + tid;
        bool ok = gm < N_NODES;
        iiS[tid] = ok ? invIn[gm] : 0.f;
        ioS[tid] = ok ? invOut[gm] : 0.f;
    }

    // A-tile load: 64 rows x 16 chunks = 1024 dwordx4, 2 per thread (coalesced)
#pragma unroll
    for (int p = 0; p < 2; ++p) {
        int task = tid + p * 512;
        int r = task >> 4, c = task & 15;
        int gm = m0 + r;
        v8h v = (gm < N_NODES) ? *(const v8h*)(A1 + (size_t)gm * K1 + c * 8)
                               : (v8h)(half_t)0;
        *(v8h*)&As[r][c * 8] = v;
    }
    __syncthreads();

    // GEMM1 -> h1S (LDS): 4 m-tiles x 2 n-tiles per wave
    for (int mt = 0; mt < 4; ++mt) {
        v8h a[4];
#pragma unroll
        for (int kc = 0; kc < 4; ++kc)
            a[kc] = *(const v8h*)&As[mt * 16 + l16][kc * 32 + quad * 8];
        v4f acc[2] = {};
#pragma unroll
        for (int kc = 0; kc < 4; ++kc)
#pragma unroll
            for (int j = 0; j < 2; ++j)
                acc[j] = __builtin_amdgcn_mfma_f32_16x16x32_f16(a[kc], b[j][kc], acc[j], 0, 0, 0);
#pragma unroll
        for (int j = 0; j < 2; ++j) {
            int cn = n0 + j * 16 + l16;
#pragma unroll
            for (int r = 0; r < 4; ++r) {
                int lr = mt * 16 + quad * 4 + r;
                float z = (acc[j][r] * iiS[lr] + bv[j]) * ioS[lr];
                h1S[lr][cn] = (half_t)fmaxf(z, 0.f);
            }
        }
    }

    // B2 fragments: 1 n-tile per wave (8 x 16 = 128 cols)
    v8h b2[8];
    const int n02 = wave * 16;
    {
        int gn = n02 + l16;
#pragma unroll
        for (int kc = 0; kc < 8; ++kc)
            b2[kc] = *(const v8h*)(Wt2 + (size_t)gn * K2 + kc * 32 + quad * 8);
    }
    __syncthreads();

    // GEMM2: t2 = h1S @ W2
    for (int mt = 0; mt < 4; ++mt) {
        v8h a2[8];
#pragma unroll
        for (int kc = 0; kc < 8; ++kc)
            a2[kc] = *(const v8h*)&h1S[mt * 16 + l16][kc * 32 + quad * 8];
        v4f acc2 = {};
#pragma unroll
        for (int kc = 0; kc < 8; ++kc)
            acc2 = __builtin_amdgcn_mfma_f32_16x16x32_f16(a2[kc], b2[kc], acc2, 0, 0, 0);
        int gn = n02 + l16;
#pragma unroll
        for (int r = 0; r < 4; ++r) {
            int gm = m0 + mt * 16 + quad * 4 + r;
            if (gm < N_NODES) t2[(size_t)gm * N2 + gn] = (half_t)acc2[r];
        }
    }
}

// ---------------- final gather (fp16 rows, fp32 out) ----------------

__global__ __launch_bounds__(256, 8) void gather_final(
    const half_t* __restrict__ x,
    const int* __restrict__ rowptr, const int* __restrict__ eidx,
    float* __restrict__ out, const float* __restrict__ invIn,
    const float* __restrict__ bias) {
    constexpr int F = 40, V = 5;
    int t = blockIdx.x * blockDim.x + threadIdx.x;
    int n = t / V;
    int v = t - n * V;
    if (n >= N_NODES) return;
    float acc[8] = {};
    gather_row<F>(x, eidx, rowptr[n], rowptr[n + 1], v, acc);
    float ii = invIn[n];
    float* o = out + (size_t)n * F + v * 8;
#pragma unroll
    for (int q = 0; q < 8; ++q) o[q] = acc[q] * ii + bias[v * 8 + q];
}

// ---------------- launch ----------------

extern "C" void kernel_launch(void* const* d_in, const int* in_sizes, int n_in,
                              void* d_out, int out_size, void* d_ws, size_t ws_size,
                              hipStream_t stream) {
    const float* x  = (const float*)d_in[0];
    const int* src  = (const int*)d_in[1];
    const int* dst  = (const int*)d_in[2];
    const float* W1 = (const float*)d_in[3];
    const float* b1 = (const float*)d_in[4];
    const float* W2 = (const float*)d_in[5];
    const float* b2 = (const float*)d_in[6];
    const float* W3 = (const float*)d_in[7];
    const float* b3 = (const float*)d_in[8];
    float* out = (float*)d_out;
    const int E = in_sizes[1];

    char* ws = (char*)d_ws;
    float* inv_out = (float*)ws;                  // 400 KB (written by scan_final)
    float* inv_in  = (float*)(ws + 400000);       // 400 KB
    int* rowptr    = (int*)(ws + 800000);         // 100001
    int* eidx      = (int*)(ws + 1600256);        // 800000 (3.2 MB)
    int* blockSum  = (int*)(ws + 4800256);        // 128
    half_t* Wt1    = (half_t*)(ws + 4800768);     // 256x128 fp16 (64 KB)
    half_t* Wt2    = (half_t*)(ws + 4866304);     // 128x256 fp16 (64 KB)
    half_t* Wt3    = (half_t*)(ws + 4931840);     // 40x128 fp16 (10 KB)
    half_t* bufA   = (half_t*)(ws + 5000192);     // 25.6 MB: xh -> t2
    half_t* bufB   = (half_t*)(ws + 30600192);    // 25.6 MB: overlays -> A1 -> t3
    // bufB overlays (all dead before gather1 writes A1):
    int* loc = (int*)bufB;                                        // E ints (3.2 MB)
    unsigned short* partialI = (unsigned short*)((char*)bufB + 3200000);  // 32xN u16 (6.4 MB)
    unsigned short* partialO = partialI + (size_t)GCOUNT * NSLICE * BINS; // 6.4 MB

    // ---- CSR + norms + weight conversion (no memset needed: everything
    //      below is fully overwritten) ----
    const int NBH = 2 * GCOUNT * NSLICE + (70656 + 511) / 512;  // 512 hist + 138 tail
    hist_all<<<NBH, 512, 0, stream>>>(src, dst, loc, partialI, partialO, E,
                                      W1, W2, W3, Wt1, Wt2, Wt3);
    scan_reduce<<<SCAN_NB, SCAN_TPB, 0, stream>>>(partialI, blockSum, N_NODES);
    scan_offsets<<<1, SCAN_NB, 0, stream>>>(blockSum, rowptr + N_NODES);
    scan_final<<<SCAN_NB, SCAN_TPB, 0, stream>>>(partialI, partialO, blockSum, rowptr,
                                                 inv_in, inv_out, N_NODES);
    prep2<<<(E + N_NODES * 32 + 255) / 256, 256, 0, stream>>>(src, dst, loc, partialI,
                                                              rowptr, eidx, E,
                                                              x, inv_out, bufA);

    const int NBG = (N_NODES * 16 + 255) / 256;  // 6250 (gather1: 16 thr/row)
    const int NB  = (N_NODES + 63) / 64;         // 1563 (mlp12: 64-row tiles)
    const int NBF = (N_NODES + 31) / 32;         // 3125 (gather2t3: 32-row tiles)

    // Layer 1 aggregation: A1 = segsum(xh)          (reads bufA, writes bufB; overlays dead)
    gather1<<<NBG, 256, 0, stream>>>(bufA, rowptr, eidx, bufB);
    // Layers 1+2 transform: t2 = MLP(A1)            (reads bufB, writes bufA; xh dead)
    mlp12<<<NB, 512, 0, stream>>>(bufB, Wt1, Wt2, inv_in, inv_out, b1, bufA);
    // Layer 2 agg + epilogue + layer 3 transform:   (reads bufA, writes bufB; A1 dead)
    //   t3 = relu((segsum(t2)*inv_in + b2)*inv_out) @ W3
    gather2t3<<<NBF, 512, 0, stream>>>(bufA, rowptr, eidx, inv_in, inv_out, b2, Wt3, bufB);
    // Final aggregation: out = segsum(t3)*inv_in+b3 (reads bufB)
    gather_final<<<(N_NODES * 5 + 255) / 256, 256, 0, stream>>>(
        bufB, rowptr, eidx, out, inv_in, b3);
}